// Round 7
// baseline (212.758 us; speedup 1.0000x reference)
//
#include <hip/hip_runtime.h>

typedef unsigned short u16;
typedef unsigned int   u32;
typedef __attribute__((ext_vector_type(8))) short s16x8;   // 8 bf16 (4 VGPRs)
typedef __attribute__((ext_vector_type(4))) float f32x4;   // MFMA accum

#define B_   2
#define S_   2048
#define HID  1024
#define NH   16
#define N3   3072
#define M_   4096
#define C2   0.36067376022224085f   // 0.25 * log2(e)  (scale folded into log2 domain)
#define OFF2 12.0f                  // stats stabilization offset, log2 domain

__device__ __forceinline__ u16 f2b(float f) {
  union { float f; u32 u; } v; v.f = f;
  u32 r = (v.u + 0x7FFFu + ((v.u >> 16) & 1u)) >> 16;   // RNE
  return (u16)r;
}

__device__ __forceinline__ u32 cvt_pk_bf16(float lo, float hi) {
  u32 r;
  asm("v_cvt_pk_bf16_f32 %0, %1, %2" : "=v"(r) : "v"(lo), "v"(hi));
  return r;
}

// async global->LDS, 16B per lane, wave-uniform LDS base (m97 pattern, GEMM only)
#define GLL(gp, lp)                                                          \
  __builtin_amdgcn_global_load_lds(                                          \
      (const __attribute__((address_space(1))) void*)(gp),                   \
      (__attribute__((address_space(3))) void*)(lp), 16, 0, 0)

// ---------------------------------------------------------------------------
// fp32 -> bf16 elementwise (x)
// ---------------------------------------------------------------------------
__global__ __launch_bounds__(256) void conv_bf16(const float* __restrict__ in,
                                                 u16* __restrict__ out, int n4) {
  int i = blockIdx.x * 256 + threadIdx.x;
  if (i >= n4) return;
  float4 v = ((const float4*)in)[i];
  ushort4 o = { f2b(v.x), f2b(v.y), f2b(v.z), f2b(v.w) };
  ((ushort4*)out)[i] = o;
}

// ---------------------------------------------------------------------------
// fp32 [K][N] -> bf16 [N][K] transpose (weights)
// ---------------------------------------------------------------------------
__global__ __launch_bounds__(256) void transpose_bf16(const float* __restrict__ in,
                                                      u16* __restrict__ out,
                                                      int K, int N) {
  __shared__ float T[32][33];
  const int t = threadIdx.x;
  const int k0 = blockIdx.y * 32, n0 = blockIdx.x * 32;
  {
    int r = t >> 3, c4 = (t & 7) * 4;
    float4 v = *(const float4*)(in + (size_t)(k0 + r) * N + n0 + c4);
    T[r][c4 + 0] = v.x; T[r][c4 + 1] = v.y; T[r][c4 + 2] = v.z; T[r][c4 + 3] = v.w;
  }
  __syncthreads();
  int n = t >> 3, kc = (t & 7) * 4;
  ushort4 o = { f2b(T[kc + 0][n]), f2b(T[kc + 1][n]), f2b(T[kc + 2][n]), f2b(T[kc + 3][n]) };
  *(ushort4*)(out + (size_t)(n0 + n) * K + k0 + kc) = o;
}

// ---------------------------------------------------------------------------
// bf16 kqv V-part -> Vt[bh][d=64][s=2048]  (LDS transpose, pitch 66)
// ---------------------------------------------------------------------------
__global__ __launch_bounds__(256) void v_transpose(const u16* __restrict__ kqv,
                                                   u16* __restrict__ Vtg) {
  __shared__ u16 Vl[64 * 66];
  const int t = threadIdx.x;
  const int bh = blockIdx.y, b = bh >> 4, h = bh & 15;
  const int s0 = blockIdx.x * 64;
  const u16* src = kqv + (size_t)b * S_ * N3 + 2 * HID + h * 64;
  #pragma unroll
  for (int cc = 0; cc < 2; ++cc) {
    int c = t + cc * 256;
    int row = c >> 3, dc = c & 7;
    uint4 v = *(const uint4*)(src + (size_t)(s0 + row) * N3 + dc * 8);
    u32* pe = (u32*)&v;
    #pragma unroll
    for (int e = 0; e < 4; ++e)
      *(u32*)(Vl + row * 66 + dc * 8 + 2 * e) = pe[e];
  }
  __syncthreads();
  #pragma unroll
  for (int cc = 0; cc < 2; ++cc) {
    int c = t + cc * 256;
    int d = c >> 3, sc = c & 7;
    u16 tmp[8];
    #pragma unroll
    for (int j = 0; j < 8; ++j) tmp[j] = Vl[(sc * 8 + j) * 66 + d];
    *(uint4*)(Vtg + ((size_t)bh * 64 + d) * S_ + s0 + sc * 8) = *(uint4*)tmp;
  }
}

// ---------------------------------------------------------------------------
// bf16 MFMA GEMM (m97 structure): C[M,N] = A[M,K] @ Bt[N,K]^T + bias
// 128x128 tile, BK=32, linear LDS [128][32], global_load_lds width 16.
// ---------------------------------------------------------------------------
template <int OUTBF16>
__global__ __launch_bounds__(256) void gemm_bf16(const u16* __restrict__ A,
                                                 const u16* __restrict__ Bt,
                                                 const float* __restrict__ bias,
                                                 void* __restrict__ Cout,
                                                 int M, int N, int K) {
  __shared__ u16 Al[128 * 32];
  __shared__ u16 Bl[128 * 32];
  const int t = threadIdx.x, lane = t & 63, w = t >> 6;
  const int m0 = blockIdx.y * 128, n0 = blockIdx.x * 128;
  const int wm = (w >> 1) * 64, wn = (w & 1) * 64;
  const int r = lane & 15, g = lane >> 4;

  f32x4 acc[4][4];
  #pragma unroll
  for (int i = 0; i < 4; ++i)
    #pragma unroll
    for (int j = 0; j < 4; ++j) acc[i][j] = (f32x4){0.f, 0.f, 0.f, 0.f};

  const int c0 = (w << 7) + lane, c1 = c0 + 64;
  const int ar0 = c0 >> 2, ak0 = (c0 & 3) << 3;
  const int ar1 = c1 >> 2, ak1 = (c1 & 3) << 3;

  for (int k0 = 0; k0 < K; k0 += 32) {
    __syncthreads();
    GLL(A  + (size_t)(m0 + ar0) * K + k0 + ak0, Al + (w << 10));
    GLL(A  + (size_t)(m0 + ar1) * K + k0 + ak1, Al + (w << 10) + 512);
    GLL(Bt + (size_t)(n0 + ar0) * K + k0 + ak0, Bl + (w << 10));
    GLL(Bt + (size_t)(n0 + ar1) * K + k0 + ak1, Bl + (w << 10) + 512);
    __syncthreads();

    s16x8 af[4], bf[4];
    #pragma unroll
    for (int mf = 0; mf < 4; ++mf)
      af[mf] = *(const s16x8*)(Al + (wm + mf * 16 + r) * 32 + g * 8);
    #pragma unroll
    for (int nf = 0; nf < 4; ++nf)
      bf[nf] = *(const s16x8*)(Bl + (wn + nf * 16 + r) * 32 + g * 8);
    #pragma unroll
    for (int mf = 0; mf < 4; ++mf)
      #pragma unroll
      for (int nf = 0; nf < 4; ++nf)
        acc[mf][nf] = __builtin_amdgcn_mfma_f32_16x16x32_bf16(af[mf], bf[nf], acc[mf][nf], 0, 0, 0);
  }

  float bv[4];
  #pragma unroll
  for (int nf = 0; nf < 4; ++nf) bv[nf] = bias[n0 + wn + nf * 16 + r];

  #pragma unroll
  for (int mf = 0; mf < 4; ++mf)
    #pragma unroll
    for (int nf = 0; nf < 4; ++nf)
      #pragma unroll
      for (int q = 0; q < 4; ++q) {
        float o = acc[mf][nf][q] + bv[nf];
        size_t idx = (size_t)(m0 + wm + mf * 16 + 4 * g + q) * N + (n0 + wn + nf * 16 + r);
        if (OUTBF16) ((u16*)Cout)[idx] = f2b(o);
        else         ((float*)Cout)[idx] = o;
      }
}

// ---------------------------------------------------------------------------
// Stats: L2[s] = OFF2 + log2( sum_n exp2(C2*K_s.Q_n - OFF2) )
// Tile 64; Q double-buffered through registers (async-STAGE): issue next-chunk
// loads, compute current from Ql[cur], ds_write to Ql[cur^1], ONE barrier/chunk.
// ---------------------------------------------------------------------------
__global__ __launch_bounds__(256) void attn_stats(const u16* __restrict__ kqv,
                                                  float* __restrict__ L2) {
  __shared__ u16 Kl[64 * 72];
  __shared__ u16 Ql[2][64 * 72];
  const int t = threadIdx.x, lane = t & 63, w = t >> 6;
  const int bh = blockIdx.y, b = bh >> 4, h = bh & 15;
  const int s0 = blockIdx.x * 64;
  const u16* base = kqv + (size_t)b * S_ * N3;
  const int r = lane & 15, g = lane >> 4;
  const int srow = t >> 3, sdc = t & 7;   // staging: rows srow, srow+32; chunk sdc

  // prologue: stage K (once) and Q chunk 0
  *(uint4*)(Kl + srow * 72 + sdc * 8) =
      *(const uint4*)(base + (size_t)(s0 + srow) * N3 + h * 64 + sdc * 8);
  *(uint4*)(Kl + (srow + 32) * 72 + sdc * 8) =
      *(const uint4*)(base + (size_t)(s0 + srow + 32) * N3 + h * 64 + sdc * 8);
  *(uint4*)(Ql[0] + srow * 72 + sdc * 8) =
      *(const uint4*)(base + (size_t)srow * N3 + HID + h * 64 + sdc * 8);
  *(uint4*)(Ql[0] + (srow + 32) * 72 + sdc * 8) =
      *(const uint4*)(base + (size_t)(srow + 32) * N3 + HID + h * 64 + sdc * 8);
  __syncthreads();

  const s16x8 ka0 = *(const s16x8*)(Kl + (w * 16 + r) * 72 + g * 8);
  const s16x8 ka1 = *(const s16x8*)(Kl + (w * 16 + r) * 72 + 32 + g * 8);

  float z[4] = {0.f, 0.f, 0.f, 0.f};

  for (int nt = 0; nt < 32; ++nt) {
    const int cur = nt & 1;
    uint4 qr0, qr1;
    if (nt < 31) {   // issue next-chunk loads early (latency hidden by compute)
      const int n1 = (nt + 1) * 64;
      qr0 = *(const uint4*)(base + (size_t)(n1 + srow) * N3 + HID + h * 64 + sdc * 8);
      qr1 = *(const uint4*)(base + (size_t)(n1 + srow + 32) * N3 + HID + h * 64 + sdc * 8);
    }
    #pragma unroll
    for (int nf = 0; nf < 4; ++nf) {
      s16x8 qb0 = *(const s16x8*)(Ql[cur] + (nf * 16 + r) * 72 + g * 8);
      s16x8 qb1 = *(const s16x8*)(Ql[cur] + (nf * 16 + r) * 72 + 32 + g * 8);
      f32x4 sc = (f32x4){0.f, 0.f, 0.f, 0.f};
      sc = __builtin_amdgcn_mfma_f32_16x16x32_bf16(ka0, qb0, sc, 0, 0, 0);
      sc = __builtin_amdgcn_mfma_f32_16x16x32_bf16(ka1, qb1, sc, 0, 0, 0);
      #pragma unroll
      for (int q = 0; q < 4; ++q)
        z[q] += exp2f(fmaf(sc[q], C2, -OFF2));
    }
    if (nt < 31) {
      *(uint4*)(Ql[cur ^ 1] + srow * 72 + sdc * 8) = qr0;
      *(uint4*)(Ql[cur ^ 1] + (srow + 32) * 72 + sdc * 8) = qr1;
    }
    __syncthreads();   // writes visible; reads of Ql[cur] complete
  }
  #pragma unroll
  for (int m = 1; m <= 8; m <<= 1)
    #pragma unroll
    for (int q = 0; q < 4; ++q) z[q] += __shfl_xor(z[q], m);
  if (r == 0)
    #pragma unroll
    for (int q = 0; q < 4; ++q)
      L2[(size_t)bh * S_ + s0 + w * 16 + 4 * g + q] = OFF2 + log2f(z[q]);
}

// ---------------------------------------------------------------------------
// PV pass: out[n,d] = sum_s exp2(C2*Q_n.K_s - L2[s]) * V[s,d]
// Tile 64; K/V double-buffered through registers, ONE barrier per chunk.
// P aliases the Q buffer (wave-private rows). P bank swizzle (round-6 proven):
// phys_chunk = logical ^ 2*((n>>2)&3).
// ---------------------------------------------------------------------------
__global__ __launch_bounds__(256) void attn_pv(const u16* __restrict__ kqv,
                                               const u16* __restrict__ Vtg,
                                               const float* __restrict__ L2,
                                               u16* __restrict__ attn) {
  __shared__ u16 QPl[64 * 72];    // Q tile, then P tile (wave-private rows)
  __shared__ u16 Kl[2][64 * 72];
  __shared__ u16 Vl[2][64 * 72];
  const int t = threadIdx.x, lane = t & 63, w = t >> 6;
  const int bh = blockIdx.y, b = bh >> 4, h = bh & 15;
  const int n0 = blockIdx.x * 64;
  const u16* base = kqv + (size_t)b * S_ * N3;
  const u16* vtb  = Vtg + (size_t)bh * 64 * S_;
  const float* Lb = L2 + (size_t)bh * S_;
  const int r = lane & 15, g = lane >> 4;
  const int srow = t >> 3, sdc = t & 7;

  // prologue: stage Q + K/V chunk 0
  *(uint4*)(QPl + srow * 72 + sdc * 8) =
      *(const uint4*)(base + (size_t)(n0 + srow) * N3 + HID + h * 64 + sdc * 8);
  *(uint4*)(QPl + (srow + 32) * 72 + sdc * 8) =
      *(const uint4*)(base + (size_t)(n0 + srow + 32) * N3 + HID + h * 64 + sdc * 8);
  *(uint4*)(Kl[0] + srow * 72 + sdc * 8) =
      *(const uint4*)(base + (size_t)srow * N3 + h * 64 + sdc * 8);
  *(uint4*)(Kl[0] + (srow + 32) * 72 + sdc * 8) =
      *(const uint4*)(base + (size_t)(srow + 32) * N3 + h * 64 + sdc * 8);
  *(uint4*)(Vl[0] + srow * 72 + sdc * 8) =
      *(const uint4*)(vtb + (size_t)srow * S_ + sdc * 8);
  *(uint4*)(Vl[0] + (srow + 32) * 72 + sdc * 8) =
      *(const uint4*)(vtb + (size_t)(srow + 32) * S_ + sdc * 8);
  __syncthreads();

  const s16x8 qa0 = *(const s16x8*)(QPl + (w * 16 + r) * 72 + g * 8);
  const s16x8 qa1 = *(const s16x8*)(QPl + (w * 16 + r) * 72 + 32 + g * 8);

  f32x4 oacc[4];
  #pragma unroll
  for (int i = 0; i < 4; ++i) oacc[i] = (f32x4){0.f, 0.f, 0.f, 0.f};

  for (int st = 0; st < 32; ++st) {
    const int cur = st & 1;
    const int s0 = st * 64;
    uint4 kr0, kr1, vr0, vr1;
    if (st < 31) {   // issue next-chunk K/V loads early
      const int s1 = s0 + 64;
      kr0 = *(const uint4*)(base + (size_t)(s1 + srow) * N3 + h * 64 + sdc * 8);
      kr1 = *(const uint4*)(base + (size_t)(s1 + srow + 32) * N3 + h * 64 + sdc * 8);
      vr0 = *(const uint4*)(vtb + (size_t)srow * S_ + s1 + sdc * 8);
      vr1 = *(const uint4*)(vtb + (size_t)(srow + 32) * S_ + s1 + sdc * 8);
    }
    float Lv[4];
    #pragma unroll
    for (int sf = 0; sf < 4; ++sf) Lv[sf] = Lb[s0 + sf * 16 + r];

    // scoreT[n][s] -> weights -> P (swizzled)
    #pragma unroll
    for (int sf = 0; sf < 4; ++sf) {
      f32x4 sc = (f32x4){0.f, 0.f, 0.f, 0.f};
      s16x8 kb0 = *(const s16x8*)(Kl[cur] + (sf * 16 + r) * 72 + g * 8);
      s16x8 kb1 = *(const s16x8*)(Kl[cur] + (sf * 16 + r) * 72 + 32 + g * 8);
      sc = __builtin_amdgcn_mfma_f32_16x16x32_bf16(qa0, kb0, sc, 0, 0, 0);
      sc = __builtin_amdgcn_mfma_f32_16x16x32_bf16(qa1, kb1, sc, 0, 0, 0);
      float p0 = exp2f(fmaf(sc[0], C2, -Lv[sf]));
      float p1 = exp2f(fmaf(sc[1], C2, -Lv[sf]));
      float p2 = exp2f(fmaf(sc[2], C2, -Lv[sf]));
      float p3 = exp2f(fmaf(sc[3], C2, -Lv[sf]));
      u32 pk01 = cvt_pk_bf16(p0, p1);
      u32 pk23 = cvt_pk_bf16(p2, p3);
      int pc = (sf * 2 + (r >> 3)) ^ (2 * g);
      int pbase = (w * 16 + 4 * g) * 72 + pc * 8 + (r & 7);
      QPl[pbase]       = (u16)pk01;           // row +0
      QPl[pbase + 72]  = (u16)(pk01 >> 16);   // row +1
      QPl[pbase + 144] = (u16)pk23;           // row +2
      QPl[pbase + 216] = (u16)(pk23 >> 16);   // row +3
    }
    // PV: P rows are wave-private; same-wave lgkm ordering suffices
    #pragma unroll
    for (int ks = 0; ks < 2; ++ks) {
      s16x8 pa = *(const s16x8*)(QPl + (w * 16 + r) * 72 +
                                 ((ks * 4 + g) ^ (2 * (r >> 2))) * 8);
      #pragma unroll
      for (int df = 0; df < 4; ++df) {
        s16x8 vb = *(const s16x8*)(Vl[cur] + (df * 16 + r) * 72 + ks * 32 + g * 8);
        oacc[df] = __builtin_amdgcn_mfma_f32_16x16x32_bf16(pa, vb, oacc[df], 0, 0, 0);
      }
    }
    if (st < 31) {   // write next chunk into the other buffer
      *(uint4*)(Kl[cur ^ 1] + srow * 72 + sdc * 8) = kr0;
      *(uint4*)(Kl[cur ^ 1] + (srow + 32) * 72 + sdc * 8) = kr1;
      *(uint4*)(Vl[cur ^ 1] + srow * 72 + sdc * 8) = vr0;
      *(uint4*)(Vl[cur ^ 1] + (srow + 32) * 72 + sdc * 8) = vr1;
    }
    __syncthreads();   // one barrier per chunk
  }

  #pragma unroll
  for (int df = 0; df < 4; ++df)
    #pragma unroll
    for (int q = 0; q < 4; ++q)
      attn[(size_t)(b * S_ + n0 + w * 16 + 4 * g + q) * HID + h * 64 + df * 16 + r] =
          f2b(oacc[df][q]);
}

// ---------------------------------------------------------------------------
extern "C" void kernel_launch(void* const* d_in, const int* in_sizes, int n_in,
                              void* d_out, int out_size, void* d_ws, size_t ws_size,
                              hipStream_t stream) {
  const float* x     = (const float*)d_in[0];
  const float* kqv_w = (const float*)d_in[1];
  const float* kqv_b = (const float*)d_in[2];
  const float* ff_w  = (const float*)d_in[3];
  const float* ff_b  = (const float*)d_in[4];
  float* out = (float*)d_out;

  u16* xb    = (u16*)d_ws;                         // 4096*1024
  u16* w1t   = xb   + (size_t)M_ * HID;            // 3072*1024
  u16* w2t   = w1t  + (size_t)N3 * HID;            // 1024*1024
  u16* kqvb  = w2t  + (size_t)HID * HID;           // 4096*3072
  u16* vtg   = kqvb + (size_t)M_ * N3;             // 32*64*2048
  float* Lr  = (float*)(vtg + (size_t)B_ * NH * 64 * S_);   // 32*2048 f32
  u16* attnb = (u16*)(Lr + (size_t)B_ * NH * S_);  // 4096*1024
  // total ~56.3 MB

  dim3 blk(256);
  conv_bf16<<<dim3((M_ * HID / 4 + 255) / 256), blk, 0, stream>>>(x, xb, M_ * HID / 4);
  transpose_bf16<<<dim3(N3 / 32, HID / 32), blk, 0, stream>>>(kqv_w, w1t, HID, N3);
  transpose_bf16<<<dim3(HID / 32, HID / 32), blk, 0, stream>>>(ff_w, w2t, HID, HID);

  gemm_bf16<1><<<dim3(N3 / 128, M_ / 128), blk, 0, stream>>>(
      xb, w1t, kqv_b, kqvb, M_, N3, HID);

  v_transpose<<<dim3(S_ / 64, B_ * NH), blk, 0, stream>>>(kqvb, vtg);
  attn_stats <<<dim3(S_ / 64, B_ * NH), blk, 0, stream>>>(kqvb, Lr);
  attn_pv    <<<dim3(S_ / 64, B_ * NH), blk, 0, stream>>>(kqvb, vtg, Lr, attnb);

  gemm_bf16<0><<<dim3(HID / 128, M_ / 128), blk, 0, stream>>>(
      attnb, w2t, ff_b, out, M_, HID, HID);
}

// Round 8
// 201.813 us; speedup vs baseline: 1.0542x; 1.0542x over previous
//
#include <hip/hip_runtime.h>

typedef unsigned short u16;
typedef unsigned int   u32;
typedef __attribute__((ext_vector_type(8))) short s16x8;   // 8 bf16 (4 VGPRs)
typedef __attribute__((ext_vector_type(4))) float f32x4;   // MFMA accum

#define B_   2
#define S_   2048
#define HID  1024
#define NH   16
#define N3   3072
#define M_   4096
#define C2   0.36067376022224085f   // 0.25 * log2(e)  (scale folded into log2 domain)
#define OFF2 12.0f                  // fixed stabilization offset, log2 domain

__device__ __forceinline__ u16 f2b(float f) {
  union { float f; u32 u; } v; v.f = f;
  u32 r = (v.u + 0x7FFFu + ((v.u >> 16) & 1u)) >> 16;   // RNE
  return (u16)r;
}

__device__ __forceinline__ float b2f(u16 x) {
  union { u32 u; float f; } v; v.u = (u32)x << 16;
  return v.f;
}

__device__ __forceinline__ u32 cvt_pk_bf16(float lo, float hi) {
  u32 r;
  asm("v_cvt_pk_bf16_f32 %0, %1, %2" : "=v"(r) : "v"(lo), "v"(hi));
  return r;
}

// async global->LDS, 16B per lane, wave-uniform LDS base (m97 pattern, GEMM only)
#define GLL(gp, lp)                                                          \
  __builtin_amdgcn_global_load_lds(                                          \
      (const __attribute__((address_space(1))) void*)(gp),                   \
      (__attribute__((address_space(3))) void*)(lp), 16, 0, 0)

// ---------------------------------------------------------------------------
// fp32 -> bf16 elementwise (x)
// ---------------------------------------------------------------------------
__global__ __launch_bounds__(256) void conv_bf16(const float* __restrict__ in,
                                                 u16* __restrict__ out, int n4) {
  int i = blockIdx.x * 256 + threadIdx.x;
  if (i >= n4) return;
  float4 v = ((const float4*)in)[i];
  ushort4 o = { f2b(v.x), f2b(v.y), f2b(v.z), f2b(v.w) };
  ((ushort4*)out)[i] = o;
}

// ---------------------------------------------------------------------------
// fp32 [K][N] -> bf16 [N][K] transpose (weights)
// ---------------------------------------------------------------------------
__global__ __launch_bounds__(256) void transpose_bf16(const float* __restrict__ in,
                                                      u16* __restrict__ out,
                                                      int K, int N) {
  __shared__ float T[32][33];
  const int t = threadIdx.x;
  const int k0 = blockIdx.y * 32, n0 = blockIdx.x * 32;
  {
    int r = t >> 3, c4 = (t & 7) * 4;
    float4 v = *(const float4*)(in + (size_t)(k0 + r) * N + n0 + c4);
    T[r][c4 + 0] = v.x; T[r][c4 + 1] = v.y; T[r][c4 + 2] = v.z; T[r][c4 + 3] = v.w;
  }
  __syncthreads();
  int n = t >> 3, kc = (t & 7) * 4;
  ushort4 o = { f2b(T[kc + 0][n]), f2b(T[kc + 1][n]), f2b(T[kc + 2][n]), f2b(T[kc + 3][n]) };
  *(ushort4*)(out + (size_t)(n0 + n) * K + k0 + kc) = o;
}

// ---------------------------------------------------------------------------
// zero the z accumulator (65536 f32)
// ---------------------------------------------------------------------------
__global__ __launch_bounds__(256) void zero_f32(float* __restrict__ p) {
  ((float4*)p)[blockIdx.x * 256 + threadIdx.x] = (float4){0.f, 0.f, 0.f, 0.f};
}

// ---------------------------------------------------------------------------
// bf16 kqv V-part -> Vt[bh][d=64][s=2048], scaled by 1/z_s (softmax fold)
// ---------------------------------------------------------------------------
__global__ __launch_bounds__(256) void v_transpose_scaled(const u16* __restrict__ kqv,
                                                          const float* __restrict__ zacc,
                                                          u16* __restrict__ Vtg) {
  __shared__ u16 Vl[64 * 66];
  const int t = threadIdx.x;
  const int bh = blockIdx.y, b = bh >> 4, h = bh & 15;
  const int s0 = blockIdx.x * 64;
  const u16* src = kqv + (size_t)b * S_ * N3 + 2 * HID + h * 64;
  #pragma unroll
  for (int cc = 0; cc < 2; ++cc) {
    int c = t + cc * 256;
    int row = c >> 3, dc = c & 7;
    uint4 v = *(const uint4*)(src + (size_t)(s0 + row) * N3 + dc * 8);
    u32* pe = (u32*)&v;
    #pragma unroll
    for (int e = 0; e < 4; ++e)
      *(u32*)(Vl + row * 66 + dc * 8 + 2 * e) = pe[e];
  }
  __syncthreads();
  #pragma unroll
  for (int cc = 0; cc < 2; ++cc) {
    int c = t + cc * 256;
    int d = c >> 3, sc = c & 7;
    float4 za = *(const float4*)(zacc + (size_t)bh * S_ + s0 + sc * 8);
    float4 zb = *(const float4*)(zacc + (size_t)bh * S_ + s0 + sc * 8 + 4);
    float zi[8] = { za.x, za.y, za.z, za.w, zb.x, zb.y, zb.z, zb.w };
    u16 tmp[8];
    #pragma unroll
    for (int j = 0; j < 8; ++j)
      tmp[j] = f2b(b2f(Vl[(sc * 8 + j) * 66 + d]) / zi[j]);
    *(uint4*)(Vtg + ((size_t)bh * 64 + d) * S_ + s0 + sc * 8) = *(uint4*)tmp;
  }
}

// ---------------------------------------------------------------------------
// bf16 MFMA GEMM (m97 structure): C[M,N] = A[M,K] @ Bt[N,K]^T + bias
// ---------------------------------------------------------------------------
template <int OUTBF16>
__global__ __launch_bounds__(256) void gemm_bf16(const u16* __restrict__ A,
                                                 const u16* __restrict__ Bt,
                                                 const float* __restrict__ bias,
                                                 void* __restrict__ Cout,
                                                 int M, int N, int K) {
  __shared__ u16 Al[128 * 32];
  __shared__ u16 Bl[128 * 32];
  const int t = threadIdx.x, lane = t & 63, w = t >> 6;
  const int m0 = blockIdx.y * 128, n0 = blockIdx.x * 128;
  const int wm = (w >> 1) * 64, wn = (w & 1) * 64;
  const int r = lane & 15, g = lane >> 4;

  f32x4 acc[4][4];
  #pragma unroll
  for (int i = 0; i < 4; ++i)
    #pragma unroll
    for (int j = 0; j < 4; ++j) acc[i][j] = (f32x4){0.f, 0.f, 0.f, 0.f};

  const int c0 = (w << 7) + lane, c1 = c0 + 64;
  const int ar0 = c0 >> 2, ak0 = (c0 & 3) << 3;
  const int ar1 = c1 >> 2, ak1 = (c1 & 3) << 3;

  for (int k0 = 0; k0 < K; k0 += 32) {
    __syncthreads();
    GLL(A  + (size_t)(m0 + ar0) * K + k0 + ak0, Al + (w << 10));
    GLL(A  + (size_t)(m0 + ar1) * K + k0 + ak1, Al + (w << 10) + 512);
    GLL(Bt + (size_t)(n0 + ar0) * K + k0 + ak0, Bl + (w << 10));
    GLL(Bt + (size_t)(n0 + ar1) * K + k0 + ak1, Bl + (w << 10) + 512);
    __syncthreads();

    s16x8 af[4], bf[4];
    #pragma unroll
    for (int mf = 0; mf < 4; ++mf)
      af[mf] = *(const s16x8*)(Al + (wm + mf * 16 + r) * 32 + g * 8);
    #pragma unroll
    for (int nf = 0; nf < 4; ++nf)
      bf[nf] = *(const s16x8*)(Bl + (wn + nf * 16 + r) * 32 + g * 8);
    #pragma unroll
    for (int mf = 0; mf < 4; ++mf)
      #pragma unroll
      for (int nf = 0; nf < 4; ++nf)
        acc[mf][nf] = __builtin_amdgcn_mfma_f32_16x16x32_bf16(af[mf], bf[nf], acc[mf][nf], 0, 0, 0);
  }

  float bv[4];
  #pragma unroll
  for (int nf = 0; nf < 4; ++nf) bv[nf] = bias[n0 + wn + nf * 16 + r];

  #pragma unroll
  for (int mf = 0; mf < 4; ++mf)
    #pragma unroll
    for (int nf = 0; nf < 4; ++nf)
      #pragma unroll
      for (int q = 0; q < 4; ++q) {
        float o = acc[mf][nf][q] + bv[nf];
        size_t idx = (size_t)(m0 + wm + mf * 16 + 4 * g + q) * N + (n0 + wn + nf * 16 + r);
        if (OUTBF16) ((u16*)Cout)[idx] = f2b(o);
        else         ((float*)Cout)[idx] = o;
      }
}

// ---------------------------------------------------------------------------
// Stats (split over n): zacc[s] += sum_{n in half} exp2(C2*K_s.Q_n - OFF2)
// grid (32 s-tiles, 32 bh, 2 halves). Round-5-proven staging, K frags hoisted.
// ---------------------------------------------------------------------------
__global__ __launch_bounds__(256) void attn_stats(const u16* __restrict__ kqv,
                                                  float* __restrict__ zacc) {
  __shared__ u16 Kl[64 * 72];
  __shared__ u16 Ql[64 * 72];
  const int t = threadIdx.x, lane = t & 63, w = t >> 6;
  const int bh = blockIdx.y, b = bh >> 4, h = bh & 15;
  const int s0 = blockIdx.x * 64;
  const int nbase = blockIdx.z * (S_ / 2);
  const u16* base = kqv + (size_t)b * S_ * N3;
  const int r = lane & 15, g = lane >> 4;

  {  // stage K tile [64 s][64 d] once
    int c = t;       int row = c >> 3, dc = c & 7;
    *(uint4*)(Kl + row * 72 + dc * 8) =
        *(const uint4*)(base + (size_t)(s0 + row) * N3 + h * 64 + dc * 8);
    c = t + 256;     row = c >> 3; dc = c & 7;
    *(uint4*)(Kl + row * 72 + dc * 8) =
        *(const uint4*)(base + (size_t)(s0 + row) * N3 + h * 64 + dc * 8);
  }
  __syncthreads();
  const s16x8 ka0 = *(const s16x8*)(Kl + (w * 16 + r) * 72 + g * 8);
  const s16x8 ka1 = *(const s16x8*)(Kl + (w * 16 + r) * 72 + 32 + g * 8);

  float z[4] = {0.f, 0.f, 0.f, 0.f};

  for (int nt = 0; nt < 16; ++nt) {
    const int n0 = nbase + nt * 64;
    __syncthreads();   // prev Q reads done
    {
      int c = t;       int row = c >> 3, dc = c & 7;
      *(uint4*)(Ql + row * 72 + dc * 8) =
          *(const uint4*)(base + (size_t)(n0 + row) * N3 + HID + h * 64 + dc * 8);
      c = t + 256;     row = c >> 3; dc = c & 7;
      *(uint4*)(Ql + row * 72 + dc * 8) =
          *(const uint4*)(base + (size_t)(n0 + row) * N3 + HID + h * 64 + dc * 8);
    }
    __syncthreads();

    #pragma unroll
    for (int nf = 0; nf < 4; ++nf) {
      s16x8 qb0 = *(const s16x8*)(Ql + (nf * 16 + r) * 72 + g * 8);
      s16x8 qb1 = *(const s16x8*)(Ql + (nf * 16 + r) * 72 + 32 + g * 8);
      f32x4 sc = (f32x4){0.f, 0.f, 0.f, 0.f};
      __builtin_amdgcn_s_setprio(1);
      sc = __builtin_amdgcn_mfma_f32_16x16x32_bf16(ka0, qb0, sc, 0, 0, 0);
      sc = __builtin_amdgcn_mfma_f32_16x16x32_bf16(ka1, qb1, sc, 0, 0, 0);
      __builtin_amdgcn_s_setprio(0);
      #pragma unroll
      for (int q = 0; q < 4; ++q)
        z[q] += exp2f(fmaf(sc[q], C2, -OFF2));
    }
  }
  #pragma unroll
  for (int m = 1; m <= 8; m <<= 1)
    #pragma unroll
    for (int q = 0; q < 4; ++q) z[q] += __shfl_xor(z[q], m);
  if (r == 0)
    #pragma unroll
    for (int q = 0; q < 4; ++q)
      atomicAdd(zacc + (size_t)bh * S_ + s0 + w * 16 + 4 * g + q, z[q]);
}

// ---------------------------------------------------------------------------
// PV pass (split over s): pout[n,d] = sum_{s in half} exp2(C2*Q.K - OFF2) * V'[s,d]
// (1/z_s pre-folded into V'.)  grid (32 n-tiles, 32 bh, 2 halves).
// Round-5 barrier structure; P aliases Q (wave-private rows, r6-proven);
// P swizzle r6-proven: write pc=(sf*2+(r>>3))^(2g), read (ks*4+g)^(2*(r>>2)).
// ---------------------------------------------------------------------------
__global__ __launch_bounds__(256) void attn_pv(const u16* __restrict__ kqv,
                                               const u16* __restrict__ Vtg,
                                               u16* __restrict__ p0,
                                               u16* __restrict__ p1) {
  __shared__ u16 QPl[64 * 72];    // Q tile, then P tile (wave-private rows)
  __shared__ u16 Kl[64 * 72];
  __shared__ u16 Vl[64 * 72];
  const int t = threadIdx.x, lane = t & 63, w = t >> 6;
  const int bh = blockIdx.y, b = bh >> 4, h = bh & 15;
  const int n0 = blockIdx.x * 64;
  const int sbase = blockIdx.z * 16;   // chunk index base
  const u16* base = kqv + (size_t)b * S_ * N3;
  const u16* vtb  = Vtg + (size_t)bh * 64 * S_;
  const int r = lane & 15, g = lane >> 4;

  {  // stage Q tile [64 n][64 d] once
    int c = t;       int row = c >> 3, dc = c & 7;
    *(uint4*)(QPl + row * 72 + dc * 8) =
        *(const uint4*)(base + (size_t)(n0 + row) * N3 + HID + h * 64 + dc * 8);
    c = t + 256;     row = c >> 3; dc = c & 7;
    *(uint4*)(QPl + row * 72 + dc * 8) =
        *(const uint4*)(base + (size_t)(n0 + row) * N3 + HID + h * 64 + dc * 8);
  }
  __syncthreads();
  const s16x8 qa0 = *(const s16x8*)(QPl + (w * 16 + r) * 72 + g * 8);
  const s16x8 qa1 = *(const s16x8*)(QPl + (w * 16 + r) * 72 + 32 + g * 8);

  f32x4 oacc[4];
  #pragma unroll
  for (int i = 0; i < 4; ++i) oacc[i] = (f32x4){0.f, 0.f, 0.f, 0.f};

  for (int st = 0; st < 16; ++st) {
    const int s0 = (sbase + st) * 64;
    __syncthreads();   // prev chunk's K/V/P reads done (iter0: Q frag reads done)
    {  // stage K [64 s][64 d] and V' [64 d][64 s]
      int c = t;       int row = c >> 3, dc = c & 7;
      *(uint4*)(Kl + row * 72 + dc * 8) =
          *(const uint4*)(base + (size_t)(s0 + row) * N3 + h * 64 + dc * 8);
      *(uint4*)(Vl + row * 72 + dc * 8) =
          *(const uint4*)(vtb + (size_t)row * S_ + s0 + dc * 8);
      c = t + 256;     row = c >> 3; dc = c & 7;
      *(uint4*)(Kl + row * 72 + dc * 8) =
          *(const uint4*)(base + (size_t)(s0 + row) * N3 + h * 64 + dc * 8);
      *(uint4*)(Vl + row * 72 + dc * 8) =
          *(const uint4*)(vtb + (size_t)row * S_ + s0 + dc * 8);
    }
    __syncthreads();

    // scoreT[n][s] -> weights (constant offset) -> P (swizzled)
    #pragma unroll
    for (int sf = 0; sf < 4; ++sf) {
      f32x4 sc = (f32x4){0.f, 0.f, 0.f, 0.f};
      s16x8 kb0 = *(const s16x8*)(Kl + (sf * 16 + r) * 72 + g * 8);
      s16x8 kb1 = *(const s16x8*)(Kl + (sf * 16 + r) * 72 + 32 + g * 8);
      __builtin_amdgcn_s_setprio(1);
      sc = __builtin_amdgcn_mfma_f32_16x16x32_bf16(qa0, kb0, sc, 0, 0, 0);
      sc = __builtin_amdgcn_mfma_f32_16x16x32_bf16(qa1, kb1, sc, 0, 0, 0);
      __builtin_amdgcn_s_setprio(0);
      float pp0 = exp2f(fmaf(sc[0], C2, -OFF2));
      float pp1 = exp2f(fmaf(sc[1], C2, -OFF2));
      float pp2 = exp2f(fmaf(sc[2], C2, -OFF2));
      float pp3 = exp2f(fmaf(sc[3], C2, -OFF2));
      u32 pk01 = cvt_pk_bf16(pp0, pp1);
      u32 pk23 = cvt_pk_bf16(pp2, pp3);
      int pc = (sf * 2 + (r >> 3)) ^ (2 * g);
      int pbase = (w * 16 + 4 * g) * 72 + pc * 8 + (r & 7);
      QPl[pbase]       = (u16)pk01;           // row +0
      QPl[pbase + 72]  = (u16)(pk01 >> 16);   // row +1
      QPl[pbase + 144] = (u16)pk23;           // row +2
      QPl[pbase + 216] = (u16)(pk23 >> 16);   // row +3
    }
    // PV: P rows are wave-private; same-wave lgkm ordering suffices
    __builtin_amdgcn_s_setprio(1);
    #pragma unroll
    for (int ks = 0; ks < 2; ++ks) {
      s16x8 pa = *(const s16x8*)(QPl + (w * 16 + r) * 72 +
                                 ((ks * 4 + g) ^ (2 * (r >> 2))) * 8);
      #pragma unroll
      for (int df = 0; df < 4; ++df) {
        s16x8 vb = *(const s16x8*)(Vl + (df * 16 + r) * 72 + ks * 32 + g * 8);
        oacc[df] = __builtin_amdgcn_mfma_f32_16x16x32_bf16(pa, vb, oacc[df], 0, 0, 0);
      }
    }
    __builtin_amdgcn_s_setprio(0);
  }

  u16* dst = blockIdx.z ? p1 : p0;
  #pragma unroll
  for (int df = 0; df < 4; ++df)
    #pragma unroll
    for (int q = 0; q < 4; ++q)
      dst[(size_t)(b * S_ + n0 + w * 16 + 4 * g + q) * HID + h * 64 + df * 16 + r] =
          f2b(oacc[df][q]);
}

// ---------------------------------------------------------------------------
// combine bf16 partials: p0 += p1 (elementwise), in place on p0
// ---------------------------------------------------------------------------
__global__ __launch_bounds__(256) void combine_halves(u16* __restrict__ p0,
                                                      const u16* __restrict__ p1) {
  int i = blockIdx.x * 256 + threadIdx.x;
  uint4 a = ((const uint4*)p0)[i];
  uint4 bq = ((const uint4*)p1)[i];
  const u16* ae = (const u16*)&a;
  const u16* be = (const u16*)&bq;
  u16 o[8];
  #pragma unroll
  for (int j = 0; j < 8; ++j) o[j] = f2b(b2f(ae[j]) + b2f(be[j]));
  ((uint4*)p0)[i] = *(uint4*)o;
}

// ---------------------------------------------------------------------------
extern "C" void kernel_launch(void* const* d_in, const int* in_sizes, int n_in,
                              void* d_out, int out_size, void* d_ws, size_t ws_size,
                              hipStream_t stream) {
  const float* x     = (const float*)d_in[0];
  const float* kqv_w = (const float*)d_in[1];
  const float* kqv_b = (const float*)d_in[2];
  const float* ff_w  = (const float*)d_in[3];
  const float* ff_b  = (const float*)d_in[4];
  float* out = (float*)d_out;

  u16* xb    = (u16*)d_ws;                         // 4096*1024  (pv partial1 later)
  u16* w1t   = xb   + (size_t)M_ * HID;            // 3072*1024
  u16* w2t   = w1t  + (size_t)N3 * HID;            // 1024*1024
  u16* kqvb  = w2t  + (size_t)HID * HID;           // 4096*3072
  u16* vtg   = kqvb + (size_t)M_ * N3;             // 32*64*2048
  float* zac = (float*)(vtg + (size_t)B_ * NH * 64 * S_);   // 32*2048 f32
  u16* attnb = (u16*)(zac + (size_t)B_ * NH * S_); // 4096*1024 (pv partial0)
  // total ~56.3 MB

  dim3 blk(256);
  conv_bf16<<<dim3(M_ * HID / 4 / 256), blk, 0, stream>>>(x, xb, M_ * HID / 4);
  transpose_bf16<<<dim3(N3 / 32, HID / 32), blk, 0, stream>>>(kqv_w, w1t, HID, N3);
  transpose_bf16<<<dim3(HID / 32, HID / 32), blk, 0, stream>>>(ff_w, w2t, HID, HID);

  gemm_bf16<1><<<dim3(N3 / 128, M_ / 128), blk, 0, stream>>>(
      xb, w1t, kqv_b, kqvb, M_, N3, HID);
  // xb is dead from here until attn_pv writes partial1 into it.

  zero_f32<<<dim3(B_ * NH * S_ / 4 / 256), blk, 0, stream>>>(zac);
  attn_stats<<<dim3(S_ / 64, B_ * NH, 2), blk, 0, stream>>>(kqvb, zac);
  v_transpose_scaled<<<dim3(S_ / 64, B_ * NH), blk, 0, stream>>>(kqvb, zac, vtg);
  attn_pv<<<dim3(S_ / 64, B_ * NH, 2), blk, 0, stream>>>(kqvb, vtg, attnb, xb);
  combine_halves<<<dim3(M_ * HID / 8 / 256), blk, 0, stream>>>(attnb, xb);

  gemm_bf16<0><<<dim3(HID / 128, M_ / 128), blk, 0, stream>>>(
      attnb, w2t, ff_b, out, M_, HID, HID);
}